// Round 7
// baseline (2122.145 us; speedup 1.0000x reference)
//
#include <hip/hip_runtime.h>
#include <cmath>

typedef __attribute__((ext_vector_type(8))) short short8v;
typedef __attribute__((ext_vector_type(4))) float float4v;
typedef __attribute__((ext_vector_type(4))) unsigned int u32x4;
typedef __attribute__((ext_vector_type(2))) unsigned int u32x2;
typedef unsigned short u16;
typedef unsigned int u32;
typedef unsigned char u8;

#define BCAP 10240

__device__ __forceinline__ u16 f2b(float f) {
  union { float f; u32 u; } v; v.f = f;
  return (u16)((v.u + 0x7fffu + ((v.u >> 16) & 1u)) >> 16);
}
__device__ __forceinline__ float lo_f(u32 u) {
  union { u32 u; float f; } v; v.u = u << 16; return v.f;
}
__device__ __forceinline__ float hi_f(u32 u) {
  union { u32 u; float f; } v; v.u = u & 0xffff0000u; return v.f;
}

// ---------------- CSR build: bucket pipeline ----------------
__global__ __launch_bounds__(256) void bucketize_kernel(const int* __restrict__ rows,
                                                        const int* __restrict__ cols,
                                                        const float* __restrict__ ew,
                                                        u32* __restrict__ gcur,
                                                        u32* __restrict__ staged_pe,
                                                        u8* __restrict__ staged_row,
                                                        int E, int NB) {
  __shared__ u32 hc[256];
  int tid = threadIdx.x;
  hc[tid] = 0;
  __syncthreads();
  int base = blockIdx.x * 8192;
  for (int k = 0; k < 32; ++k) {
    int i = base + k * 256 + tid;
    if (i < E) atomicAdd(&hc[((u32)rows[i]) >> 8], 1);
  }
  __syncthreads();
  u32 myb = 0;
  u32 mycnt = (tid < NB) ? hc[tid] : 0;
  if (mycnt) myb = atomicAdd(&gcur[tid], mycnt);
  __syncthreads();
  hc[tid] = myb;
  __syncthreads();
  for (int k = 0; k < 32; ++k) {
    int i = base + k * 256 + tid;
    if (i < E) {
      u32 r = (u32)rows[i];
      u32 b = r >> 8;
      u32 pos = atomicAdd(&hc[b], 1);
      if (pos < BCAP) {
        u32 wq = (u32)(ew[i] * 65536.0f);
        if (wq > 65535u) wq = 65535u;
        size_t si = (size_t)b * BCAP + pos;
        staged_pe[si] = (wq << 16) | (u32)cols[i];
        staged_row[si] = (u8)(r & 255u);
      }
    }
  }
}

__global__ __launch_bounds__(256) void bscan_kernel(const u32* __restrict__ gcur,
                                                    u32* __restrict__ bbase, int NB,
                                                    int* __restrict__ rowptrN, int E) {
  __shared__ u32 sd[256];
  int tid = threadIdx.x;
  u32 v = (tid < NB) ? gcur[tid] : 0;
  sd[tid] = v;
  __syncthreads();
  for (int o = 1; o < 256; o <<= 1) {
    u32 t = (tid >= o) ? sd[tid - o] : 0;
    __syncthreads();
    sd[tid] += t;
    __syncthreads();
  }
  if (tid < NB) bbase[tid] = sd[tid] - v;
  if (tid == 0) *rowptrN = E;
}

__global__ __launch_bounds__(256) void bsort_kernel(const u32* __restrict__ gcur,
                                                    const u32* __restrict__ bbase,
                                                    const u32* __restrict__ staged_pe,
                                                    const u8* __restrict__ staged_row,
                                                    u32* __restrict__ pe,
                                                    int* __restrict__ rowptr, int n) {
  __shared__ u32 rh[256];
  __shared__ u32 sd[256];
  __shared__ u32 rcur[256];
  int b = blockIdx.x, tid = threadIdx.x;
  u32 cnt = gcur[b];
  if (cnt > BCAP) cnt = BCAP;
  u32 base = bbase[b];
  rh[tid] = 0;
  __syncthreads();
  const u32* sp = staged_pe + (size_t)b * BCAP;
  const u8* sr = staged_row + (size_t)b * BCAP;
  for (u32 idx = tid; idx < cnt; idx += 256) atomicAdd(&rh[sr[idx]], 1);
  __syncthreads();
  u32 v = rh[tid];
  sd[tid] = v;
  __syncthreads();
  for (int o = 1; o < 256; o <<= 1) {
    u32 t = (tid >= o) ? sd[tid - o] : 0;
    __syncthreads();
    sd[tid] += t;
    __syncthreads();
  }
  u32 excl = sd[tid] - v;
  int gr = b * 256 + tid;
  if (gr < n) rowptr[gr] = (int)(base + excl);
  rcur[tid] = base + excl;
  __syncthreads();
  for (u32 idx = tid; idx < cnt; idx += 256) {
    u32 pos = atomicAdd(&rcur[sr[idx]], 1);
    pe[pos] = sp[idx];
  }
}

// ---------------- conversions ----------------
// W1 [N,256] f32 -> panel-major bf16 [8][NP][32]
__global__ __launch_bounds__(256) void cvt_w1_kernel(const float* __restrict__ in,
                                                     u16* __restrict__ outb, int n, int NP) {
  int tid = blockIdx.x * 256 + threadIdx.x;
  if (tid >= n * 8) return;
  int node = tid >> 3, q = tid & 7, panel = blockIdx.y;
  float4 v = *(const float4*)(in + (size_t)node * 256 + panel * 32 + q * 4);
  u32x2 o;
  o[0] = (u32)f2b(v.x) | ((u32)f2b(v.y) << 16);
  o[1] = (u32)f2b(v.z) | ((u32)f2b(v.w) << 16);
  *(u32x2*)(outb + ((size_t)panel * NP + node) * 32 + q * 4) = o;
}

// B'[l][n][k] = bf16( theta_l * Wc[l][k][n] + (1-theta_l)*(k==n) )  via LDS transpose
__global__ __launch_bounds__(256) void cvt_wc_kernel(const float* __restrict__ in,
                                                     u16* __restrict__ outb) {
  __shared__ u16 t[64][68];
  int l = blockIdx.z;
  int k0 = blockIdx.y << 6, n0 = blockIdx.x << 6;
  float theta = logf(0.1f / (float)(l + 1) + 1.0f);
  float omt = 1.0f - theta;
  int kk = threadIdx.x >> 2;
  int nq = (threadIdx.x & 3) << 4;
  const float* ip = in + ((size_t)l << 16) + ((size_t)(k0 + kk) << 8) + n0 + nq;
  int gk = k0 + kk;
#pragma unroll
  for (int q = 0; q < 16; q += 4) {
    float4 v = *(const float4*)(ip + q);
    float fv[4] = {v.x, v.y, v.z, v.w};
#pragma unroll
    for (int x = 0; x < 4; ++x) {
      int gn = n0 + nq + q + x;
      float f = theta * fv[x];
      if (gk == gn) f += omt;
      t[nq + q + x][kk] = f2b(f);
    }
  }
  __syncthreads();
  int nn = threadIdx.x >> 2;
  int kq = (threadIdx.x & 3) << 4;
  u16* op = outb + ((size_t)l << 16) + ((size_t)(n0 + nn) << 8) + k0 + kq;
  u32x4 w0, w1;
#pragma unroll
  for (int x = 0; x < 4; ++x) {
    w0[x] = (u32)t[nn][kq + 2 * x] | ((u32)t[nn][kq + 2 * x + 1] << 16);
    w1[x] = (u32)t[nn][kq + 8 + 2 * x] | ((u32)t[nn][kq + 8 + 2 * x + 1] << 16);
  }
  *(u32x4*)op = w0;
  *(u32x4*)(op + 8) = w1;
}

// ---------------- panel SpMM: XCD-pinned panels, 32 edges in flight ----------------
// panel = bid & 7 (round-robin over 8 XCDs -> each XCD's L2 caches one 3.2MB panel)
// 8 edge-slots x 8 lanes; lane owns 4 cols (u32x2 = 8B); groups of 4 unrolled.
__global__ __launch_bounds__(256) void spmm1_kernel(const int* __restrict__ rowptr,
                                                    const u32* __restrict__ pe,
                                                    const u16* __restrict__ Xp,
                                                    u16* __restrict__ outp, int n, int NP) {
  int bid = blockIdx.x;
  int panel = bid & 7;
  int row = (bid >> 3) * 4 + (threadIdx.x >> 6);
  if (row >= n) return;
  int lane = threadIdx.x & 63;
  int slot = lane >> 3, cl = lane & 7;
  const u16* X = Xp + (size_t)panel * NP * 32;
  int s = rowptr[row], e = rowptr[row + 1];
  float a0 = 0, a1 = 0, a2 = 0, a3 = 0;
  for (int j0 = s; j0 < e; j0 += 32) {
    u32 p[4];
#pragma unroll
    for (int g = 0; g < 4; ++g) {
      int j = j0 + (g << 3) + slot;
      p[g] = __builtin_nontemporal_load(pe + ((j < e) ? j : (e - 1)));
    }
    u32x2 v[4];
#pragma unroll
    for (int g = 0; g < 4; ++g)
      v[g] = *(const u32x2*)(X + ((size_t)(p[g] & 0xFFFFu) << 5) + (cl << 2));
#pragma unroll
    for (int g = 0; g < 4; ++g) {
      float wv = (float)(p[g] >> 16) * (1.0f / 65536.0f);
      if (j0 + (g << 3) + slot >= e) wv = 0.f;
      a0 = fmaf(wv, lo_f(v[g][0]), a0);
      a1 = fmaf(wv, hi_f(v[g][0]), a1);
      a2 = fmaf(wv, lo_f(v[g][1]), a2);
      a3 = fmaf(wv, hi_f(v[g][1]), a3);
    }
  }
#pragma unroll
  for (int m = 8; m < 64; m <<= 1) {
    a0 += __shfl_xor(a0, m); a1 += __shfl_xor(a1, m);
    a2 += __shfl_xor(a2, m); a3 += __shfl_xor(a3, m);
  }
  if (lane < 8) {
    u32x2 o;
    o[0] = (u32)f2b(fmaxf(a0, 0.f)) | ((u32)f2b(fmaxf(a1, 0.f)) << 16);
    o[1] = (u32)f2b(fmaxf(a2, 0.f)) | ((u32)f2b(fmaxf(a3, 0.f)) << 16);
    __builtin_nontemporal_store(
        o, (u32x2*)(outp + ((size_t)panel * NP + row) * 32 + (cl << 2)));
  }
}

__global__ __launch_bounds__(256) void spmm_blend_kernel(const int* __restrict__ rowptr,
                                                         const u32* __restrict__ pe,
                                                         const u16* __restrict__ Xp,
                                                         const u16* __restrict__ anchor,
                                                         u16* __restrict__ outp,
                                                         int n, int NP) {
  int bid = blockIdx.x;
  int panel = bid & 7;
  int row = (bid >> 3) * 4 + (threadIdx.x >> 6);
  if (row >= n) return;
  int lane = threadIdx.x & 63;
  int slot = lane >> 3, cl = lane & 7;
  const u16* X = Xp + (size_t)panel * NP * 32;
  int s = rowptr[row], e = rowptr[row + 1];
  float a0 = 0, a1 = 0, a2 = 0, a3 = 0;
  for (int j0 = s; j0 < e; j0 += 32) {
    u32 p[4];
#pragma unroll
    for (int g = 0; g < 4; ++g) {
      int j = j0 + (g << 3) + slot;
      p[g] = __builtin_nontemporal_load(pe + ((j < e) ? j : (e - 1)));
    }
    u32x2 v[4];
#pragma unroll
    for (int g = 0; g < 4; ++g)
      v[g] = *(const u32x2*)(X + ((size_t)(p[g] & 0xFFFFu) << 5) + (cl << 2));
#pragma unroll
    for (int g = 0; g < 4; ++g) {
      float wv = (float)(p[g] >> 16) * (1.0f / 65536.0f);
      if (j0 + (g << 3) + slot >= e) wv = 0.f;
      a0 = fmaf(wv, lo_f(v[g][0]), a0);
      a1 = fmaf(wv, hi_f(v[g][0]), a1);
      a2 = fmaf(wv, lo_f(v[g][1]), a2);
      a3 = fmaf(wv, hi_f(v[g][1]), a3);
    }
  }
#pragma unroll
  for (int m = 8; m < 64; m <<= 1) {
    a0 += __shfl_xor(a0, m); a1 += __shfl_xor(a1, m);
    a2 += __shfl_xor(a2, m); a3 += __shfl_xor(a3, m);
  }
  if (lane < 8) {
    size_t off = ((size_t)panel * NP + row) * 32 + (cl << 2);
    u32x2 av = __builtin_nontemporal_load((const u32x2*)(anchor + off));
    u32x2 o;
    o[0] = (u32)f2b(0.9f * a0 + 0.1f * lo_f(av[0])) |
           ((u32)f2b(0.9f * a1 + 0.1f * hi_f(av[0])) << 16);
    o[1] = (u32)f2b(0.9f * a2 + 0.1f * lo_f(av[1])) |
           ((u32)f2b(0.9f * a3 + 0.1f * hi_f(av[1])) << 16);
    __builtin_nontemporal_store(o, (u32x2*)(outp + off));
  }
}

// ---------------- dense GEMM: Hout = relu(A @ B'), panel-major A & Hout ----------------
__global__ __launch_bounds__(128) void gemm_kernel(const u16* __restrict__ A,
                                                   const u16* __restrict__ B,
                                                   u16* __restrict__ Hout, int NP) {
  __shared__ u16 tile[64 * 264];
  int wave = threadIdx.x >> 6;
  int lane = threadIdx.x & 63;
  int m0 = blockIdx.x * 64 + wave * 32;
  int r0 = m0 + (lane & 15);
  int khalf = (lane >> 4) << 3;  // 0,8,16,24 (col within panel)
  const u16* Bp = B + ((lane & 15) << 8) + khalf;

  float4v acc0[16], acc1[16];
#pragma unroll
  for (int i = 0; i < 16; ++i) {
    acc0[i] = (float4v){0.f, 0.f, 0.f, 0.f};
    acc1[i] = (float4v){0.f, 0.f, 0.f, 0.f};
  }
#pragma unroll
  for (int ks = 0; ks < 8; ++ks) {  // ks == panel index
    const u16* Ap = A + ((size_t)ks * NP + r0) * 32 + khalf;
    short8v a0 = *(const short8v*)Ap;
    short8v a1 = *(const short8v*)(Ap + 512);  // +16 rows
#pragma unroll
    for (int nf = 0; nf < 16; ++nf) {
      short8v b = *(const short8v*)(Bp + (nf << 12) + (ks << 5));
      acc0[nf] = __builtin_amdgcn_mfma_f32_16x16x32_bf16(a0, b, acc0[nf], 0, 0, 0);
      acc1[nf] = __builtin_amdgcn_mfma_f32_16x16x32_bf16(a1, b, acc1[nf], 0, 0, 0);
    }
  }
  int lrbase = wave * 32 + ((lane >> 4) << 2);
  int ccol = lane & 15;
#pragma unroll
  for (int nf = 0; nf < 16; ++nf) {
    int col = (nf << 4) + ccol;
#pragma unroll
    for (int j = 0; j < 4; ++j) {
      tile[(lrbase + j) * 264 + col] = f2b(fmaxf(acc0[nf][j], 0.f));
      tile[(lrbase + j + 16) * 264 + col] = f2b(fmaxf(acc1[nf][j], 0.f));
    }
  }
  __syncthreads();
  // panel-major store: idx -> (panel, row, quad)
#pragma unroll
  for (int it = 0; it < 16; ++it) {
    int idx = it * 128 + threadIdx.x;
    int quad = idx & 3;
    int lr = (idx >> 2) & 63;
    int panel = idx >> 8;
    u32x4 v = *(const u32x4*)(tile + lr * 264 + (panel << 5) + (quad << 3));
    __builtin_nontemporal_store(
        v, (u32x4*)(Hout + ((size_t)panel * NP + (size_t)blockIdx.x * 64 + lr) * 32 +
                    (quad << 3)));
  }
}

// ---------------- h @ W2 (256 -> 10), h panel-major ----------------
__global__ __launch_bounds__(256) void gemm2_kernel(const u16* __restrict__ Hb,
                                                    const float* __restrict__ W2,
                                                    float* __restrict__ g, int n, int NP) {
  __shared__ float sW2[2560];
  for (int i = threadIdx.x; i < 2560; i += 256) sW2[i] = W2[i];
  __syncthreads();
  int idx = blockIdx.x * 256 + threadIdx.x;
  if (idx >= n * 10) return;
  int r = idx / 10, c = idx - r * 10;
  float acc = 0.f;
#pragma unroll
  for (int p = 0; p < 8; ++p) {
    const u16* bp = Hb + ((size_t)p * NP + r) * 32;
    const float* wp = sW2 + p * 320 + c;
    u32x4 v0 = *(const u32x4*)bp;
    u32x4 v1 = *(const u32x4*)(bp + 8);
    u32x4 v2 = *(const u32x4*)(bp + 16);
    u32x4 v3 = *(const u32x4*)(bp + 24);
#pragma unroll
    for (int q = 0; q < 4; ++q) {
      acc = fmaf(lo_f(v0[q]), wp[(2 * q) * 10], acc);
      acc = fmaf(hi_f(v0[q]), wp[(2 * q + 1) * 10], acc);
      acc = fmaf(lo_f(v1[q]), wp[(8 + 2 * q) * 10], acc);
      acc = fmaf(hi_f(v1[q]), wp[(8 + 2 * q + 1) * 10], acc);
      acc = fmaf(lo_f(v2[q]), wp[(16 + 2 * q) * 10], acc);
      acc = fmaf(hi_f(v2[q]), wp[(16 + 2 * q + 1) * 10], acc);
      acc = fmaf(lo_f(v3[q]), wp[(24 + 2 * q) * 10], acc);
      acc = fmaf(hi_f(v3[q]), wp[(24 + 2 * q + 1) * 10], acc);
    }
  }
  g[idx] = acc;
}

// ---------------- final SpMM on [N,10] f32 ----------------
__global__ __launch_bounds__(256) void spmm_final_kernel(const int* __restrict__ rowptr,
                                                         const u32* __restrict__ pe,
                                                         const float* __restrict__ g,
                                                         float* __restrict__ out, int n) {
  int row = blockIdx.x * 4 + (threadIdx.x >> 6);
  if (row >= n) return;
  int lane = threadIdx.x & 63;
  int es = lane / 10;
  int c = lane - es * 10;
  bool active = lane < 60;
  int s = rowptr[row], e = rowptr[row + 1];
  float acc = 0.f;
  for (int j6 = s; j6 < e; j6 += 24) {
#pragma unroll
    for (int u = 0; u < 4; ++u) {
      int j = j6 + 6 * u + es;
      int jc = (j < e) ? j : (e - 1);
      u32 p = __builtin_nontemporal_load(pe + jc);
      float wv = (float)(p >> 16) * (1.0f / 65536.0f);
      if (!active || j >= e) wv = 0.f;
      acc = fmaf(wv, g[(size_t)(p & 0xFFFFu) * 10 + c], acc);
    }
  }
  float a0 = acc;
  acc = a0 + __shfl(a0, lane + 10, 64) + __shfl(a0, lane + 20, 64) +
        __shfl(a0, lane + 30, 64) + __shfl(a0, lane + 40, 64) + __shfl(a0, lane + 50, 64);
  if (lane < 10) out[(size_t)row * 10 + lane] = acc;
}

extern "C" void kernel_launch(void* const* d_in, const int* in_sizes, int n_in,
                              void* d_out, int out_size, void* d_ws, size_t ws_size,
                              hipStream_t stream) {
  const int* rows = (const int*)d_in[1];
  const int* cols = (const int*)d_in[2];
  const float* ew = (const float*)d_in[3];
  const float* W1 = (const float*)d_in[4];
  const float* Wc = (const float*)d_in[5];
  const float* W2 = (const float*)d_in[6];
  float* out = (float*)d_out;
  const int N = in_sizes[0];
  const int E = in_sizes[1];
  const int L = in_sizes[5] >> 16;
  const int NP = ((N + 127) / 128) * 128;
  const int NB = (N + 255) >> 8;

  char* w = (char*)d_ws;
  size_t off = 0;
  auto carve = [&](size_t bytes) -> char* {
    char* p = w + off;
    off = (off + bytes + 255) & ~(size_t)255;
    return p;
  };
  int* rowptr = (int*)carve(((size_t)N + 1) * 4);
  u32* gcur = (u32*)carve(256 * 4);
  u32* bbase = (u32*)carve(256 * 4);
  u32* pe = (u32*)carve((size_t)E * 4);
  u16* Wcb = (u16*)carve((size_t)L * 65536 * 2);
  u16* layer0 = (u16*)carve((size_t)NP * 512);
  u16* bufA = (u16*)carve((size_t)NP * 512);
  u16* bufB = (u16*)carve((size_t)NP * 512);
  u16* suppt = (u16*)carve((size_t)NP * 512);
  float* g = (float*)carve((size_t)NP * 40);
  u16* W1b = (u16*)carve((size_t)NP * 512);
  u32* staged_pe = (u32*)((void*)bufA);  // CSR-build staging overlays bufA/bufB region
  u8* staged_row = (u8*)bufA + (size_t)NB * BCAP * 4;

  int nb4 = (N + 3) / 4;

  // CSR build: bucketize -> scan -> per-bucket sort
  (void)hipMemsetAsync(gcur, 0, 256 * 4, stream);
  bucketize_kernel<<<(E + 8191) / 8192, 256, 0, stream>>>(rows, cols, ew, gcur,
                                                          staged_pe, staged_row, E, NB);
  bscan_kernel<<<1, 256, 0, stream>>>(gcur, bbase, NB, rowptr + N, E);
  bsort_kernel<<<NB, 256, 0, stream>>>(gcur, bbase, staged_pe, staged_row, pe, rowptr, N);

  // weight conversions
  cvt_wc_kernel<<<dim3(4, 4, L), 256, 0, stream>>>(Wc, Wcb);
  cvt_w1_kernel<<<dim3((N * 8 + 255) / 256, 8), 256, 0, stream>>>(W1, W1b, N, NP);

  // layer1 (panel spmm)
  spmm1_kernel<<<nb4 * 8, 256, 0, stream>>>(rowptr, pe, W1b, layer0, N, NP);

  // 8 GCNII layers: panel spmm+blend -> MFMA gemm
  const u16* hin = layer0;
  int half = L / 2;
  for (int i = 0; i < L; ++i) {
    const u16* anchor = (i <= half) ? hin : layer0;
    spmm_blend_kernel<<<nb4 * 8, 256, 0, stream>>>(rowptr, pe, hin, anchor, suppt, N, NP);
    u16* hout = (hin == bufA) ? bufB : ((hin == bufB) ? bufA : bufB);
    gemm_kernel<<<NP / 64, 128, 0, stream>>>(suppt, Wcb + (size_t)i * 65536, hout, NP);
    hin = hout;
  }

  // layer2
  gemm2_kernel<<<(N * 10 + 255) / 256, 256, 0, stream>>>(hin, W2, g, N, NP);
  spmm_final_kernel<<<nb4, 256, 0, stream>>>(rowptr, pe, g, out, N);
}